// Round 14
// baseline (1857.552 us; speedup 1.0000x reference)
//
#include <hip/hip_runtime.h>
#include <stdint.h>
#include <math.h>

#define BB 8
#define NN 16384
#define CC 13
#define GG 512
#define KK 32

#define FB 4          // fps blocks per batch
#define CHUNK 4096    // points per fps block

#define NEIGH_ELEMS (BB*GG*KK*CC)   // 1,703,936

// ---------------------------------------------------------------------------
// DPP wave(64) arg-reductions: 6 VALU stages, result valid in LANE 63 only.
// bound_ctrl=false, old=self: invalid lanes combine with themselves (no-op
// for idempotent combine). Strict compare + lower-index tiebreak is
// commutative+associative -> tree exact. VALU pipe, no DS latency.
// ---------------------------------------------------------------------------
__device__ __forceinline__ void wave_argmax_dpp(float& v, int& p) {
    int vi = __float_as_int(v);
    int pi = p;
#define ARGMAX_STAGE(CTRL)                                                   \
    {                                                                        \
        int nv = __builtin_amdgcn_update_dpp(vi, vi, CTRL, 0xF, 0xF, false); \
        int np = __builtin_amdgcn_update_dpp(pi, pi, CTRL, 0xF, 0xF, false); \
        float a = __int_as_float(nv);                                        \
        float b = __int_as_float(vi);                                        \
        if (a > b || (a == b && np < pi)) { vi = nv; pi = np; }              \
    }
    ARGMAX_STAGE(0x111)  // row_shr:1
    ARGMAX_STAGE(0x112)  // row_shr:2
    ARGMAX_STAGE(0x114)  // row_shr:4
    ARGMAX_STAGE(0x118)  // row_shr:8
    ARGMAX_STAGE(0x142)  // row_bcast:15
    ARGMAX_STAGE(0x143)  // row_bcast:31
#undef ARGMAX_STAGE
    v = __int_as_float(vi);
    p = pi;
}

__device__ __forceinline__ void wave_argmin_dpp(float& v, int& p) {
    int vi = __float_as_int(v);
    int pi = p;
#define ARGMIN_STAGE(CTRL)                                                   \
    {                                                                        \
        int nv = __builtin_amdgcn_update_dpp(vi, vi, CTRL, 0xF, 0xF, false); \
        int np = __builtin_amdgcn_update_dpp(pi, pi, CTRL, 0xF, 0xF, false); \
        float a = __int_as_float(nv);                                        \
        float b = __int_as_float(vi);                                        \
        if (a < b || (a == b && np < pi)) { vi = nv; pi = np; }              \
    }
    ARGMIN_STAGE(0x111)  // row_shr:1
    ARGMIN_STAGE(0x112)  // row_shr:2
    ARGMIN_STAGE(0x114)  // row_shr:4
    ARGMIN_STAGE(0x118)  // row_shr:8
    ARGMIN_STAGE(0x142)  // row_bcast:15
    ARGMIN_STAGE(0x143)  // row_bcast:31
#undef ARGMIN_STAGE
    v = __int_as_float(vi);
    p = pi;
}

// Relaxed agent-scope 64-bit mailbox ops. Scope guarantees the access is
// serviced at the device coherence point (cross-XCD visible); the packed
// word carries tag+payload so no ordering fences are needed.
__device__ __forceinline__ unsigned long long mbox_load(const unsigned long long* p) {
    return __hip_atomic_load(p, __ATOMIC_RELAXED, __HIP_MEMORY_SCOPE_AGENT);
}
__device__ __forceinline__ void mbox_store(unsigned long long* p, unsigned long long v) {
    __hip_atomic_store(p, v, __ATOMIC_RELAXED, __HIP_MEMORY_SCOPE_AGENT);
}

// ---------------------------------------------------------------------------
// Pack: x[B,N,13] (fp32) -> f32 SoA planes px,py,pz (channels 4..6).
// Also zeroes the 64 fps mailbox slots (they live in d_out; knn overwrites
// that region later, and stream order makes this race-free).
// ---------------------------------------------------------------------------
__global__ void pack_kernel(const float* __restrict__ x,
                            float* __restrict__ px, float* __restrict__ py,
                            float* __restrict__ pz,
                            unsigned long long* __restrict__ mbox) {
    int i = blockIdx.x * blockDim.x + threadIdx.x;
    if (blockIdx.x == 0 && threadIdx.x < 64) mbox[threadIdx.x * 8] = 0ull;
    if (i >= BB * NN) return;
    const float* p = x + (size_t)i * CC + 4;
    px[i] = p[0]; py[i] = p[1]; pz[i] = p[2];
}

// ---------------------------------------------------------------------------
// FPS v9: 4 blocks/batch (32 blocks), 1024 threads, 4 pts/thread, point
// coords in LDS. R13 post-mortem: v8 (8 pts/thread) still spilled
// (VGPR_Count=28 < 32 persistent floats) -> this compiler will NOT hold
// bulk per-thread state in registers for these kernels, full stop (five
// configs: 88/44/52/52/28 regs, attributes + named scalars all ineffective;
// VALU bloat ~3-4x from scratch round-trips each time). v9 puts coords in
// LDS (deterministic ~6cyc throughput, no RA involvement): xs/ys/zs[4096]
// = 48KB static. Loop-carried reg state shrinks to 4 md floats (+ scalars)
// -- smaller than the 28 regs the RA demonstrably grants. Each thread
// reads back only its own 4 points (LDS as software-managed scratch).
// Mailbox: v8's proven scheme extended to 3 partners (k^1,k^2,k^3),
// overlapped polling; slot(b,k,par), 64B stride; tag(g)<<46|f32<<14|idx.
// Blocks of a batch share an XCD (blk&7=batch). Tie-break at every level:
// strict compare, lower flat index == np.argmax first-occurrence. fp32
// distance math verbatim (bit-exact).
// ---------------------------------------------------------------------------
__global__ __launch_bounds__(1024)
void fps_kernel(const float* __restrict__ px,
                const float* __restrict__ py,
                const float* __restrict__ pz,
                float* __restrict__ centers,
                unsigned long long* __restrict__ mbox) {
    const int blk = blockIdx.x;
    const int b = blk & 7;        // batch (same XCD for all 4 blocks of b)
    const int k = blk >> 3;       // chunk: 0..3
    const int t = threadIdx.x;
    const int base = k * CHUNK;   // k<<12
    const float* PX = px + b * NN;
    const float* PY = py + b * NN;
    const float* PZ = pz + b * NN;

    __shared__ float xs[CHUNK], ys[CHUNK], zs[CHUNK];   // 48 KB
    __shared__ float s_v[2][16];
    __shared__ int   s_p[2][16];

    // stage my chunk into LDS (each thread writes/reads only its own 4 pts;
    // same-thread LDS RAW is ordered by lgkmcnt, no barrier needed)
#pragma unroll
    for (int i = 0; i < 4; ++i) {
        int j = t + (i << 10);
        xs[j] = PX[base + j];
        ys[j] = PY[base + j];
        zs[j] = PZ[base + j];
    }
    float md0 = 1e10f, md1 = 1e10f, md2 = 1e10f, md3 = 1e10f;  // init_d

    // mailbox slot(b,k,par) = (b*8 + k*2 + par) u64-index*8 -> 64B stride
    unsigned long long* my_slot = mbox + (((b << 3) | (k << 1)) << 3);
    unsigned long long* pa = mbox + (((b << 3) | ((k ^ 1) << 1)) << 3);
    unsigned long long* pb = mbox + (((b << 3) | ((k ^ 2) << 1)) << 3);
    unsigned long long* pc = mbox + (((b << 3) | ((k ^ 3) << 1)) << 3);

    int wp = 0;   // current center index (uniform across all 4 blocks)
    if (k == 0 && t == 0) {
        float* oc = centers + (size_t)b * GG * 3;
        oc[0] = PX[0]; oc[1] = PY[0]; oc[2] = PZ[0];
    }

    for (int g = 1; g < GG; ++g) {
        // scalar broadcast load of current center coords (uniform index)
        int swp = __builtin_amdgcn_readfirstlane(wp);
        float lx = PX[swp], ly = PY[swp], lz = PZ[swp];
        float bv = -1.0f;
        int bi = 0;   // best local point index 0..3 (compile-time consts)
#define STEPPT(i)                                                            \
    {                                                                        \
        float xx = xs[t + (i << 10)];                                        \
        float yy = ys[t + (i << 10)];                                        \
        float zz = zs[t + (i << 10)];                                        \
        float e0 = __fsub_rn(xx, lx);                                        \
        float e1 = __fsub_rn(yy, ly);                                        \
        float e2 = __fsub_rn(zz, lz);                                        \
        float d  = __fadd_rn(__fadd_rn(__fmul_rn(e0, e0), __fmul_rn(e1, e1)),\
                             __fmul_rn(e2, e2));                             \
        float m = fminf(md##i, d); /* np.minimum */                          \
        md##i = m;                                                           \
        if (m > bv) { bv = m; bi = i; }                                      \
    }
        STEPPT(0) STEPPT(1) STEPPT(2) STEPPT(3)
#undef STEPPT
        int bp = base + t + (bi << 10);   // global flat pos, ascending in i
        wave_argmax_dpp(bv, bp);          // result in lane 63
        int par = g & 1;
        if ((t & 63) == 63) { s_v[par][t >> 6] = bv; s_p[par][t >> 6] = bp; }
        __syncthreads();
        // block-local best: redundant 16-partial scan by every thread
        float lv = s_v[par][0]; int lp = s_p[par][0];
#pragma unroll
        for (int q = 1; q < 16; ++q) {
            float qv = s_v[par][q]; int qp = s_p[par][q];
            if (qv > lv || (qv == lv && qp < lp)) { lv = qv; lp = qp; }
        }
        // publish my chunk's best; poll 3 partners with overlapped loads
        if (t == 0) {
            unsigned long long pk = ((unsigned long long)g << 46)
                                  | ((unsigned long long)(unsigned)__float_as_int(lv) << 14)
                                  | (unsigned long long)(unsigned)lp;
            mbox_store(my_slot + par * 8, pk);
        }
        unsigned long long v1 = 0, v2 = 0, v3 = 0;
        bool ok1 = false, ok2 = false, ok3 = false;
        int guard = 0;
        do {
            if (!ok1) { v1 = mbox_load(pa + par * 8); ok1 = ((int)(v1 >> 46) == g); }
            if (!ok2) { v2 = mbox_load(pb + par * 8); ok2 = ((int)(v2 >> 46) == g); }
            if (!ok3) { v3 = mbox_load(pc + par * 8); ok3 = ((int)(v3 >> 46) == g); }
        } while (!(ok1 && ok2 && ok3) && ++guard < (1 << 26));
        // combine 4 chunk-bests: global argmax, tie -> lower flat index
        float gv = lv; int gp = lp;
#define COMBINE(vw)                                                          \
    {                                                                        \
        float pv = __int_as_float((int)(((vw) >> 14) & 0xFFFFFFFFull));      \
        int   pp = (int)((vw) & 0x3FFFull);                                  \
        if (pv > gv || (pv == gv && pp < gp)) { gv = pv; gp = pp; }          \
    }
        COMBINE(v1) COMBINE(v2) COMBINE(v3)
#undef COMBINE
        wp = gp;
        if (k == 0 && t == 0) {
            float* oc = centers + ((size_t)b * GG + g) * 3;
            oc[0] = PX[wp]; oc[1] = PY[wp]; oc[2] = PZ[wp];
        }
        // parity LDS buffers: write of par(g+2)==par(g) happens after
        // barrier(g+1), which follows every thread's scan at g -> race-free
    }
}

// ---------------------------------------------------------------------------
// KNN v3 + gather (unchanged math) + XCD swizzle: batch b's 512 blocks map
// to one XCD (blockIdx round-robins XCDs by %8) so the 196 KB SoA stays
// L2-resident per XCD. Per-round wave argmin via DPP.
// ---------------------------------------------------------------------------
__global__ __launch_bounds__(256, 8) void knn_kernel(const float* __restrict__ px,
                                                     const float* __restrict__ py,
                                                     const float* __restrict__ pz,
                                                     const float* __restrict__ x,
                                                     const float* __restrict__ centers,
                                                     float* __restrict__ out) {
    const int blk = blockIdx.x;
    const int bg  = ((blk & 7) << 9) | (blk >> 3);   // batch = blk&7 -> one XCD
    const int b   = bg >> 9;
    const int t   = threadIdx.x;

    const float* ctr = centers + (size_t)bg * 3;
    float cx = ctr[0], cy = ctr[1], cz = ctr[2];
    float cc2 = __fadd_rn(__fadd_rn(__fmul_rn(cx, cx), __fmul_rn(cy, cy)),
                          __fmul_rn(cz, cz));

    const float* PX = px + b * NN;
    const float* PY = py + b * NN;
    const float* PZ = pz + b * NN;

    float k1 = INFINITY, k2 = INFINITY;
    int   p1 = 0x7fffffff, p2 = 0x7fffffff;
    uint64_t mask = 0;   // consumed elements of my 64-pt chunk

#pragma unroll 4
    for (int i = 0; i < 64; ++i) {
        int pos = (i << 8) + t;           // coalesced
        float ax = PX[pos], ay = PY[pos], az = PZ[pos];
        float pp2 = __fadd_rn(__fadd_rn(__fmul_rn(ax, ax), __fmul_rn(ay, ay)),
                              __fmul_rn(az, az));
        float dot = fmaf(cz, az, fmaf(cy, ay, __fmul_rn(cx, ax)));
        float d2  = __fsub_rn(__fadd_rn(cc2, pp2), __fmul_rn(2.0f, dot));
        // ascending pos scan, strict '<': ties keep lower pos
        if (d2 < k1)      { k2 = k1; p2 = p1; k1 = d2; p1 = pos; }
        else if (d2 < k2) { k2 = d2; p2 = pos; }
    }

    __shared__ float s_v[2][4];
    __shared__ int   s_p[2][4];
    __shared__ int   s_chosen[KK];

    for (int j = 0; j < KK; ++j) {
        float v = k1; int vp = p1;
        // wave(64) DPP argmin, tie -> lower pos; result in lane 63
        wave_argmin_dpp(v, vp);
        int par = j & 1;
        if ((t & 63) == 63) { s_v[par][t >> 6] = v; s_p[par][t >> 6] = vp; }
        __syncthreads();
        // redundant scan of 4 partials by every thread
        float wv = s_v[par][0]; int wp = s_p[par][0];
#pragma unroll
        for (int q = 1; q < 4; ++q) {
            float qv = s_v[par][q]; int qp = s_p[par][q];
            if (qv < wv || (qv == wv && qp < wp)) { wv = qv; wp = qp; }
        }
        if (t == 0) s_chosen[j] = wp;
        if ((wp & 255) == t) {
            // I owned the extracted point: mark consumed, promote second
            mask |= 1ull << (wp >> 8);
            k1 = k2; p1 = p2;
            k2 = INFINITY; p2 = 0x7fffffff;
            if (p1 == 0x7fffffff && mask != 0xffffffffffffffffull) {
                // top-2 exhausted (rare): rebuild from unmasked points,
                // reloading coords from global; d2 bit-identical
                k1 = INFINITY;
#pragma unroll 1
                for (int i = 0; i < 64; ++i) {
                    if ((mask >> i) & 1ull) continue;
                    int pos = (i << 8) + t;
                    float ax = PX[pos], ay = PY[pos], az = PZ[pos];
                    float pp2 = __fadd_rn(__fadd_rn(__fmul_rn(ax, ax), __fmul_rn(ay, ay)),
                                          __fmul_rn(az, az));
                    float dot = fmaf(cz, az, fmaf(cy, ay, __fmul_rn(cx, ax)));
                    float d2  = __fsub_rn(__fadd_rn(cc2, pp2), __fmul_rn(2.0f, dot));
                    if (d2 < k1)      { k2 = k1; p2 = p1; k1 = d2; p1 = pos; }
                    else if (d2 < k2) { k2 = d2; p2 = pos; }
                }
            }
        }
        // no second barrier: parity buffer isolates next round's writes
    }
    __syncthreads();   // s_chosen visibility for gather

    // gather: 32 neighbors x 13 channels; subtract center from ch 4..6
    for (int v = t; v < KK * CC; v += 256) {
        int j = v / CC, c = v - j * CC;
        int pt = s_chosen[j] & (NN - 1);   // safety clamp (no-op when correct)
        float val = x[((size_t)b * NN + pt) * CC + c];
        if (c >= 4 && c < 7) {
            float cs = (c == 4) ? cx : ((c == 5) ? cy : cz);
            val = __fsub_rn(val, cs);
        }
        out[((size_t)bg * KK + j) * CC + c] = val;
    }
}

extern "C" void kernel_launch(void* const* d_in, const int* in_sizes, int n_in,
                              void* d_out, int out_size, void* d_ws, size_t ws_size,
                              hipStream_t stream) {
    const float* x = (const float*)d_in[0];
    float* out = (float*)d_out;
    float* centers = out + NEIGH_ELEMS;   // output 1 follows output 0, flat

    float* px = (float*)d_ws;
    float* py = px + BB * NN;
    float* pz = py + BB * NN;

    // fps mailbox lives in the first 4KB of the neighbor-output region;
    // pack zeroes it (stream-ordered before fps), knn overwrites it after.
    unsigned long long* mbox = (unsigned long long*)d_out;

    pack_kernel<<<(BB * NN + 255) / 256, 256, 0, stream>>>(x, px, py, pz, mbox);
    fps_kernel<<<FB * BB, 1024, 0, stream>>>(px, py, pz, centers, mbox);
    knn_kernel<<<BB * GG, 256, 0, stream>>>(px, py, pz, x, centers, out);
}

// Round 16
// 1448.726 us; speedup vs baseline: 1.2822x; 1.2822x over previous
//
#include <hip/hip_runtime.h>
#include <stdint.h>
#include <math.h>

#define BB 8
#define NN 16384
#define CC 13
#define GG 512
#define KK 32

#define NEIGH_ELEMS (BB*GG*KK*CC)   // 1,703,936

// ---------------------------------------------------------------------------
// DPP wave(64) arg-reductions: 6 VALU stages, result valid in LANE 63 only.
// bound_ctrl=false, old=self: invalid lanes combine with themselves (no-op
// for idempotent combine). Strict compare + lower-index tiebreak is
// commutative+associative -> tree exact. VALU pipe, no DS latency.
// ---------------------------------------------------------------------------
__device__ __forceinline__ void wave_argmax_dpp(float& v, int& p) {
    int vi = __float_as_int(v);
    int pi = p;
#define ARGMAX_STAGE(CTRL)                                                   \
    {                                                                        \
        int nv = __builtin_amdgcn_update_dpp(vi, vi, CTRL, 0xF, 0xF, false); \
        int np = __builtin_amdgcn_update_dpp(pi, pi, CTRL, 0xF, 0xF, false); \
        float a = __int_as_float(nv);                                        \
        float b = __int_as_float(vi);                                        \
        if (a > b || (a == b && np < pi)) { vi = nv; pi = np; }              \
    }
    ARGMAX_STAGE(0x111)  // row_shr:1
    ARGMAX_STAGE(0x112)  // row_shr:2
    ARGMAX_STAGE(0x114)  // row_shr:4
    ARGMAX_STAGE(0x118)  // row_shr:8
    ARGMAX_STAGE(0x142)  // row_bcast:15
    ARGMAX_STAGE(0x143)  // row_bcast:31
#undef ARGMAX_STAGE
    v = __int_as_float(vi);
    p = pi;
}

__device__ __forceinline__ void wave_argmin_dpp(float& v, int& p) {
    int vi = __float_as_int(v);
    int pi = p;
#define ARGMIN_STAGE(CTRL)                                                   \
    {                                                                        \
        int nv = __builtin_amdgcn_update_dpp(vi, vi, CTRL, 0xF, 0xF, false); \
        int np = __builtin_amdgcn_update_dpp(pi, pi, CTRL, 0xF, 0xF, false); \
        float a = __int_as_float(nv);                                        \
        float b = __int_as_float(vi);                                        \
        if (a < b || (a == b && np < pi)) { vi = nv; pi = np; }              \
    }
    ARGMIN_STAGE(0x111)  // row_shr:1
    ARGMIN_STAGE(0x112)  // row_shr:2
    ARGMIN_STAGE(0x114)  // row_shr:4
    ARGMIN_STAGE(0x118)  // row_shr:8
    ARGMIN_STAGE(0x142)  // row_bcast:15
    ARGMIN_STAGE(0x143)  // row_bcast:31
#undef ARGMIN_STAGE
    v = __int_as_float(vi);
    p = pi;
}

// ---------------------------------------------------------------------------
// Pack: x[B,N,13] (fp32) -> f32 SoA planes px,py,pz (channels 4..6).
// ---------------------------------------------------------------------------
__global__ void pack_kernel(const float* __restrict__ x,
                            float* __restrict__ px, float* __restrict__ py,
                            float* __restrict__ pz) {
    int i = blockIdx.x * blockDim.x + threadIdx.x;
    if (i >= BB * NN) return;
    const float* p = x + (size_t)i * CC + 4;
    px[i] = p[0]; py[i] = p[1]; pz[i] = p[2];
}

// ---------------------------------------------------------------------------
// FPS v10: back to the BEST MEASURED structure (v4: one block/batch, 512
// threads, 32 pts/thread, 1095us) with its one defect fixed via LDS.
// R14 post-mortem: v9 (4 blocks, LDS coords, 3-way mailbox) had ZERO spills
// (VGPR=16) and was the SLOWEST fps yet (1616us, 7590cyc/step vs ~400cyc
// compute) -- the per-step cross-block exchange through device-coherent
// memory costs ~HBM latency per step (FETCH 809->2200KB = mailbox traffic).
// Every multi-block variant regressed (1095->1437->1464->1616): FPS's 511
// serial steps cannot afford memory-mediated sync. v10: single block again,
// no mailbox. v4's spill (state 128 f32 > 88 granted regs) is fixed by
// moving Y,Z into 128KB dynamic LDS as float2[16384] (160KB/CU available,
// one block/CU; 128KB/workgroup proven in plain HIP). Register state = X[32]
// + MD[32] = 64 + ~24 temps ~= 88 = exactly the RA's demonstrated grant at
// 512 threads. Each thread stages and reads ONLY its own 32 points -> no
// staging barrier (same-thread LDS RAW ordered by lgkmcnt); ds_read_b64,
// 2-way bank aliasing (free). fp32 math verbatim (bit-exact); ascending
// scan + strict '>' + lower-flat-index ties == np.argmax first-occurrence.
// ---------------------------------------------------------------------------
__global__ __launch_bounds__(512, 2)
void fps_kernel(const float* __restrict__ px,
                const float* __restrict__ py,
                const float* __restrict__ pz,
                float* __restrict__ centers) {
    const int b = blockIdx.x;
    const int t = threadIdx.x;
    const float* PX = px + b * NN;
    const float* PY = py + b * NN;
    const float* PZ = pz + b * NN;

    extern __shared__ float2 yz[];   // [NN] = 128 KB dynamic

    float X[32], MD[32];
#pragma unroll
    for (int i = 0; i < 32; ++i) {
        int pos = t + (i << 9);
        X[i] = PX[pos];
        yz[pos] = make_float2(PY[pos], PZ[pos]);
        MD[i] = 1e10f;   // init_d = 10000000000.0
        asm volatile("" : "+v"(X[i]));   // block remat of the X loads
    }

    __shared__ float s_v[2][8];
    __shared__ int   s_p[2][8];

    int wp = 0;   // current center index (uniform across block)
    if (t == 0) {
        float* oc = centers + (size_t)b * GG * 3;
        oc[0] = PX[0]; oc[1] = PY[0]; oc[2] = PZ[0];
    }

    for (int g = 1; g < GG; ++g) {
        // scalar broadcast load of current center coords (uniform index)
        int swp = __builtin_amdgcn_readfirstlane(wp);
        float lx = PX[swp], ly = PY[swp], lz = PZ[swp];
        float bv = -1.0f;
        int bi = 0;   // best local point index 0..31 (inline-const cndmask)
#pragma unroll
        for (int i = 0; i < 32; ++i) {
            int pos = t + (i << 9);
            float2 p2 = yz[pos];           // ds_read_b64, own slot only
            float e0 = __fsub_rn(X[i], lx);
            float e1 = __fsub_rn(p2.x, ly);
            float e2 = __fsub_rn(p2.y, lz);
            float d  = __fadd_rn(__fadd_rn(__fmul_rn(e0, e0), __fmul_rn(e1, e1)),
                                 __fmul_rn(e2, e2));
            float m = fminf(MD[i], d);     // np.minimum
            MD[i] = m;
            // ascending-index scan + strict '>' keeps lowest index on ties
            if (m > bv) { bv = m; bi = i; }
        }
        int bp = t + (bi << 9);   // flat pos; ascending i == ascending pos
        // wave(64) DPP argmax, tie -> lower flat index; result in lane 63
        wave_argmax_dpp(bv, bp);
        int par = g & 1;
        if ((t & 63) == 63) { s_v[par][t >> 6] = bv; s_p[par][t >> 6] = bp; }
        __syncthreads();
        // redundant scan of 8 partials by every thread (LDS broadcast reads)
        float wv = s_v[par][0]; int wi = s_p[par][0];
#pragma unroll
        for (int q = 1; q < 8; ++q) {
            float qv = s_v[par][q]; int qp = s_p[par][q];
            if (qv > wv || (qv == wv && qp < wi)) { wv = qv; wi = qp; }
        }
        wp = wi;
        if (t == 0) {
            float* oc = centers + ((size_t)b * GG + g) * 3;
            oc[0] = PX[wp]; oc[1] = PY[wp]; oc[2] = PZ[wp];
        }
        // no second barrier: parity buffer isolates next round's writes
    }
}

// ---------------------------------------------------------------------------
// KNN v3 + gather (unchanged math) + XCD swizzle: batch b's 512 blocks map
// to one XCD (blockIdx round-robins XCDs by %8) so the 196 KB SoA stays
// L2-resident per XCD. Per-round wave argmin via DPP.
// ---------------------------------------------------------------------------
__global__ __launch_bounds__(256, 8) void knn_kernel(const float* __restrict__ px,
                                                     const float* __restrict__ py,
                                                     const float* __restrict__ pz,
                                                     const float* __restrict__ x,
                                                     const float* __restrict__ centers,
                                                     float* __restrict__ out) {
    const int blk = blockIdx.x;
    const int bg  = ((blk & 7) << 9) | (blk >> 3);   // batch = blk&7 -> one XCD
    const int b   = bg >> 9;
    const int t   = threadIdx.x;

    const float* ctr = centers + (size_t)bg * 3;
    float cx = ctr[0], cy = ctr[1], cz = ctr[2];
    float cc2 = __fadd_rn(__fadd_rn(__fmul_rn(cx, cx), __fmul_rn(cy, cy)),
                          __fmul_rn(cz, cz));

    const float* PX = px + b * NN;
    const float* PY = py + b * NN;
    const float* PZ = pz + b * NN;

    float k1 = INFINITY, k2 = INFINITY;
    int   p1 = 0x7fffffff, p2 = 0x7fffffff;
    uint64_t mask = 0;   // consumed elements of my 64-pt chunk

#pragma unroll 4
    for (int i = 0; i < 64; ++i) {
        int pos = (i << 8) + t;           // coalesced
        float ax = PX[pos], ay = PY[pos], az = PZ[pos];
        float pp2 = __fadd_rn(__fadd_rn(__fmul_rn(ax, ax), __fmul_rn(ay, ay)),
                              __fmul_rn(az, az));
        float dot = fmaf(cz, az, fmaf(cy, ay, __fmul_rn(cx, ax)));
        float d2  = __fsub_rn(__fadd_rn(cc2, pp2), __fmul_rn(2.0f, dot));
        // ascending pos scan, strict '<': ties keep lower pos
        if (d2 < k1)      { k2 = k1; p2 = p1; k1 = d2; p1 = pos; }
        else if (d2 < k2) { k2 = d2; p2 = pos; }
    }

    __shared__ float s_v[2][4];
    __shared__ int   s_p[2][4];
    __shared__ int   s_chosen[KK];

    for (int j = 0; j < KK; ++j) {
        float v = k1; int vp = p1;
        // wave(64) DPP argmin, tie -> lower pos; result in lane 63
        wave_argmin_dpp(v, vp);
        int par = j & 1;
        if ((t & 63) == 63) { s_v[par][t >> 6] = v; s_p[par][t >> 6] = vp; }
        __syncthreads();
        // redundant scan of 4 partials by every thread
        float wv = s_v[par][0]; int wp = s_p[par][0];
#pragma unroll
        for (int q = 1; q < 4; ++q) {
            float qv = s_v[par][q]; int qp = s_p[par][q];
            if (qv < wv || (qv == wv && qp < wp)) { wv = qv; wp = qp; }
        }
        if (t == 0) s_chosen[j] = wp;
        if ((wp & 255) == t) {
            // I owned the extracted point: mark consumed, promote second
            mask |= 1ull << (wp >> 8);
            k1 = k2; p1 = p2;
            k2 = INFINITY; p2 = 0x7fffffff;
            if (p1 == 0x7fffffff && mask != 0xffffffffffffffffull) {
                // top-2 exhausted (rare): rebuild from unmasked points,
                // reloading coords from global; d2 bit-identical
                k1 = INFINITY;
#pragma unroll 1
                for (int i = 0; i < 64; ++i) {
                    if ((mask >> i) & 1ull) continue;
                    int pos = (i << 8) + t;
                    float ax = PX[pos], ay = PY[pos], az = PZ[pos];
                    float pp2 = __fadd_rn(__fadd_rn(__fmul_rn(ax, ax), __fmul_rn(ay, ay)),
                                          __fmul_rn(az, az));
                    float dot = fmaf(cz, az, fmaf(cy, ay, __fmul_rn(cx, ax)));
                    float d2  = __fsub_rn(__fadd_rn(cc2, pp2), __fmul_rn(2.0f, dot));
                    if (d2 < k1)      { k2 = k1; p2 = p1; k1 = d2; p1 = pos; }
                    else if (d2 < k2) { k2 = d2; p2 = pos; }
                }
            }
        }
        // no second barrier: parity buffer isolates next round's writes
    }
    __syncthreads();   // s_chosen visibility for gather

    // gather: 32 neighbors x 13 channels; subtract center from ch 4..6
    for (int v = t; v < KK * CC; v += 256) {
        int j = v / CC, c = v - j * CC;
        int pt = s_chosen[j] & (NN - 1);   // safety clamp (no-op when correct)
        float val = x[((size_t)b * NN + pt) * CC + c];
        if (c >= 4 && c < 7) {
            float cs = (c == 4) ? cx : ((c == 5) ? cy : cz);
            val = __fsub_rn(val, cs);
        }
        out[((size_t)bg * KK + j) * CC + c] = val;
    }
}

extern "C" void kernel_launch(void* const* d_in, const int* in_sizes, int n_in,
                              void* d_out, int out_size, void* d_ws, size_t ws_size,
                              hipStream_t stream) {
    const float* x = (const float*)d_in[0];
    float* out = (float*)d_out;
    float* centers = out + NEIGH_ELEMS;   // output 1 follows output 0, flat

    float* px = (float*)d_ws;
    float* py = px + BB * NN;
    float* pz = py + BB * NN;

    // one-time opt-in for >64KB dynamic LDS on fps_kernel (host-side
    // attribute set; not a stream op, graph-capture safe)
    static bool lds_cfg = false;
    if (!lds_cfg) {
        hipFuncSetAttribute((const void*)fps_kernel,
                            hipFuncAttributeMaxDynamicSharedMemorySize,
                            NN * (int)sizeof(float2));
        lds_cfg = true;
    }

    pack_kernel<<<(BB * NN + 255) / 256, 256, 0, stream>>>(x, px, py, pz);
    fps_kernel<<<BB, 512, NN * sizeof(float2), stream>>>(px, py, pz, centers);
    knn_kernel<<<BB * GG, 256, 0, stream>>>(px, py, pz, x, centers, out);
}

// Round 18
// 1345.646 us; speedup vs baseline: 1.3804x; 1.0766x over previous
//
#include <hip/hip_runtime.h>
#include <stdint.h>
#include <math.h>

#define BB 8
#define NN 16384
#define CC 13
#define GG 512
#define KK 32

#define NEIGH_ELEMS (BB*GG*KK*CC)   // 1,703,936

// ---------------------------------------------------------------------------
// DPP wave(64) arg-reductions: 6 VALU stages, result valid in LANE 63 only.
// bound_ctrl=false, old=self: invalid lanes combine with themselves (no-op
// for idempotent combine). Strict compare + lower-index tiebreak is
// commutative+associative -> tree exact. VALU pipe, no DS latency.
// ---------------------------------------------------------------------------
__device__ __forceinline__ void wave_argmax_dpp(float& v, int& p) {
    int vi = __float_as_int(v);
    int pi = p;
#define ARGMAX_STAGE(CTRL)                                                   \
    {                                                                        \
        int nv = __builtin_amdgcn_update_dpp(vi, vi, CTRL, 0xF, 0xF, false); \
        int np = __builtin_amdgcn_update_dpp(pi, pi, CTRL, 0xF, 0xF, false); \
        float a = __int_as_float(nv);                                        \
        float b = __int_as_float(vi);                                        \
        if (a > b || (a == b && np < pi)) { vi = nv; pi = np; }              \
    }
    ARGMAX_STAGE(0x111)  // row_shr:1
    ARGMAX_STAGE(0x112)  // row_shr:2
    ARGMAX_STAGE(0x114)  // row_shr:4
    ARGMAX_STAGE(0x118)  // row_shr:8
    ARGMAX_STAGE(0x142)  // row_bcast:15
    ARGMAX_STAGE(0x143)  // row_bcast:31
#undef ARGMAX_STAGE
    v = __int_as_float(vi);
    p = pi;
}

__device__ __forceinline__ void wave_argmin_dpp(float& v, int& p) {
    int vi = __float_as_int(v);
    int pi = p;
#define ARGMIN_STAGE(CTRL)                                                   \
    {                                                                        \
        int nv = __builtin_amdgcn_update_dpp(vi, vi, CTRL, 0xF, 0xF, false); \
        int np = __builtin_amdgcn_update_dpp(pi, pi, CTRL, 0xF, 0xF, false); \
        float a = __int_as_float(nv);                                        \
        float b = __int_as_float(vi);                                        \
        if (a < b || (a == b && np < pi)) { vi = nv; pi = np; }              \
    }
    ARGMIN_STAGE(0x111)  // row_shr:1
    ARGMIN_STAGE(0x112)  // row_shr:2
    ARGMIN_STAGE(0x114)  // row_shr:4
    ARGMIN_STAGE(0x118)  // row_shr:8
    ARGMIN_STAGE(0x142)  // row_bcast:15
    ARGMIN_STAGE(0x143)  // row_bcast:31
#undef ARGMIN_STAGE
    v = __int_as_float(vi);
    p = pi;
}

// ---------------------------------------------------------------------------
// Pack: x[B,N,13] (fp32) -> f32 SoA planes px,py,pz (channels 4..6).
// ---------------------------------------------------------------------------
__global__ void pack_kernel(const float* __restrict__ x,
                            float* __restrict__ px, float* __restrict__ py,
                            float* __restrict__ pz) {
    int i = blockIdx.x * blockDim.x + threadIdx.x;
    if (i >= BB * NN) return;
    const float* p = x + (size_t)i * CC + 4;
    px[i] = p[0]; py[i] = p[1]; pz[i] = p[2];
}

// ---------------------------------------------------------------------------
// FPS v11: EXACT v4 structure (best measured: 1095us, R1) + waves_per_eu(2,2).
// Measured series: v4 1095 (88 regs, partial spill) / v6-v7 1403 (52) /
// v8 1464 (28, mailbox) / v9 1616 (16, no-spill but sync-bound) / v10 1194
// (64, LDS-yz but DS-pipe floor ~= VALU floor + still spilled temps).
// Lessons: cross-block sync >= 1us/step (dead end); LDS offload trades
// spill VALU for equal DS cost. The untested lever: v4's launch_bounds
// (512,2) already ALLOWED 256 regs yet the RA chose 88 (targets ~5
// waves/EU beyond the declared min). waves_per_eu(2,2) caps the occupancy
// TARGET at 2 waves/EU (= exactly one resident 8-wave block; grid is 8
// blocks on 256 CUs, so >1 block/CU never exists) -> RA budget 256 >=
// the ~152 this kernel needs for X/Y/Z/MD + temps. Only change vs the
// 1095us kernel is the attribute: single-variable, downside bounded at
// the best-known result. fp32 math verbatim (bit-exact); ascending scan
// + strict '>' + lower-flat-index ties == np.argmax first-occurrence.
// ---------------------------------------------------------------------------
__global__ __launch_bounds__(512)
__attribute__((amdgpu_waves_per_eu(2, 2)))
void fps_kernel(const float* __restrict__ px,
                const float* __restrict__ py,
                const float* __restrict__ pz,
                float* __restrict__ centers) {
    const int b = blockIdx.x;
    const int t = threadIdx.x;
    const float* PX = px + b * NN;
    const float* PY = py + b * NN;
    const float* PZ = pz + b * NN;

    float X[32], Y[32], Z[32], MD[32];
#pragma unroll
    for (int i = 0; i < 32; ++i) {
        int pos = t + (i << 9);
        X[i] = PX[pos]; Y[i] = PY[pos]; Z[i] = PZ[pos];
        MD[i] = 1e10f;   // init_d = 10000000000.0
        // Pin: mark values as asm-modified so the loads cannot be
        // rematerialized inside the step loop.
        asm volatile("" : "+v"(X[i]), "+v"(Y[i]), "+v"(Z[i]));
    }

    __shared__ float s_v[2][8];
    __shared__ int   s_p[2][8];

    int wp = 0;   // current center index (uniform across block)
    if (t == 0) {
        float* oc = centers + (size_t)b * GG * 3;
        oc[0] = PX[0]; oc[1] = PY[0]; oc[2] = PZ[0];
    }

    for (int g = 1; g < GG; ++g) {
        // scalar broadcast load of current center coords (uniform index)
        int swp = __builtin_amdgcn_readfirstlane(wp);
        float lx = PX[swp], ly = PY[swp], lz = PZ[swp];
        float bv = -1.0f;
        int bi = 0;   // best local point index 0..31 (inline-const cndmask)
#pragma unroll
        for (int i = 0; i < 32; ++i) {
            float e0 = __fsub_rn(X[i], lx);
            float e1 = __fsub_rn(Y[i], ly);
            float e2 = __fsub_rn(Z[i], lz);
            float d  = __fadd_rn(__fadd_rn(__fmul_rn(e0, e0), __fmul_rn(e1, e1)),
                                 __fmul_rn(e2, e2));
            float m = fminf(MD[i], d);   // np.minimum
            MD[i] = m;
            // ascending-index scan + strict '>' keeps lowest index on ties
            if (m > bv) { bv = m; bi = i; }
        }
        int bp = t + (bi << 9);   // flat pos; ascending i == ascending pos
        // wave(64) DPP argmax, tie -> lower flat index; result in lane 63
        wave_argmax_dpp(bv, bp);
        int par = g & 1;
        if ((t & 63) == 63) { s_v[par][t >> 6] = bv; s_p[par][t >> 6] = bp; }
        __syncthreads();
        // redundant scan of 8 partials by every thread (LDS broadcast reads)
        float wv = s_v[par][0]; int wi = s_p[par][0];
#pragma unroll
        for (int q = 1; q < 8; ++q) {
            float qv = s_v[par][q]; int qp = s_p[par][q];
            if (qv > wv || (qv == wv && qp < wi)) { wv = qv; wi = qp; }
        }
        wp = wi;
        if (t == 0) {
            float* oc = centers + ((size_t)b * GG + g) * 3;
            oc[0] = PX[wp]; oc[1] = PY[wp]; oc[2] = PZ[wp];
        }
        // no second barrier: parity buffer isolates next round's writes
    }
}

// ---------------------------------------------------------------------------
// KNN v3 + gather (unchanged math) + XCD swizzle: batch b's 512 blocks map
// to one XCD (blockIdx round-robins XCDs by %8) so the 196 KB SoA stays
// L2-resident per XCD. Per-round wave argmin via DPP.
// ---------------------------------------------------------------------------
__global__ __launch_bounds__(256, 8) void knn_kernel(const float* __restrict__ px,
                                                     const float* __restrict__ py,
                                                     const float* __restrict__ pz,
                                                     const float* __restrict__ x,
                                                     const float* __restrict__ centers,
                                                     float* __restrict__ out) {
    const int blk = blockIdx.x;
    const int bg  = ((blk & 7) << 9) | (blk >> 3);   // batch = blk&7 -> one XCD
    const int b   = bg >> 9;
    const int t   = threadIdx.x;

    const float* ctr = centers + (size_t)bg * 3;
    float cx = ctr[0], cy = ctr[1], cz = ctr[2];
    float cc2 = __fadd_rn(__fadd_rn(__fmul_rn(cx, cx), __fmul_rn(cy, cy)),
                          __fmul_rn(cz, cz));

    const float* PX = px + b * NN;
    const float* PY = py + b * NN;
    const float* PZ = pz + b * NN;

    float k1 = INFINITY, k2 = INFINITY;
    int   p1 = 0x7fffffff, p2 = 0x7fffffff;
    uint64_t mask = 0;   // consumed elements of my 64-pt chunk

#pragma unroll 4
    for (int i = 0; i < 64; ++i) {
        int pos = (i << 8) + t;           // coalesced
        float ax = PX[pos], ay = PY[pos], az = PZ[pos];
        float pp2 = __fadd_rn(__fadd_rn(__fmul_rn(ax, ax), __fmul_rn(ay, ay)),
                              __fmul_rn(az, az));
        float dot = fmaf(cz, az, fmaf(cy, ay, __fmul_rn(cx, ax)));
        float d2  = __fsub_rn(__fadd_rn(cc2, pp2), __fmul_rn(2.0f, dot));
        // ascending pos scan, strict '<': ties keep lower pos
        if (d2 < k1)      { k2 = k1; p2 = p1; k1 = d2; p1 = pos; }
        else if (d2 < k2) { k2 = d2; p2 = pos; }
    }

    __shared__ float s_v[2][4];
    __shared__ int   s_p[2][4];
    __shared__ int   s_chosen[KK];

    for (int j = 0; j < KK; ++j) {
        float v = k1; int vp = p1;
        // wave(64) DPP argmin, tie -> lower pos; result in lane 63
        wave_argmin_dpp(v, vp);
        int par = j & 1;
        if ((t & 63) == 63) { s_v[par][t >> 6] = v; s_p[par][t >> 6] = vp; }
        __syncthreads();
        // redundant scan of 4 partials by every thread
        float wv = s_v[par][0]; int wp = s_p[par][0];
#pragma unroll
        for (int q = 1; q < 4; ++q) {
            float qv = s_v[par][q]; int qp = s_p[par][q];
            if (qv < wv || (qv == wv && qp < wp)) { wv = qv; wp = qp; }
        }
        if (t == 0) s_chosen[j] = wp;
        if ((wp & 255) == t) {
            // I owned the extracted point: mark consumed, promote second
            mask |= 1ull << (wp >> 8);
            k1 = k2; p1 = p2;
            k2 = INFINITY; p2 = 0x7fffffff;
            if (p1 == 0x7fffffff && mask != 0xffffffffffffffffull) {
                // top-2 exhausted (rare): rebuild from unmasked points,
                // reloading coords from global; d2 bit-identical
                k1 = INFINITY;
#pragma unroll 1
                for (int i = 0; i < 64; ++i) {
                    if ((mask >> i) & 1ull) continue;
                    int pos = (i << 8) + t;
                    float ax = PX[pos], ay = PY[pos], az = PZ[pos];
                    float pp2 = __fadd_rn(__fadd_rn(__fmul_rn(ax, ax), __fmul_rn(ay, ay)),
                                          __fmul_rn(az, az));
                    float dot = fmaf(cz, az, fmaf(cy, ay, __fmul_rn(cx, ax)));
                    float d2  = __fsub_rn(__fadd_rn(cc2, pp2), __fmul_rn(2.0f, dot));
                    if (d2 < k1)      { k2 = k1; p2 = p1; k1 = d2; p1 = pos; }
                    else if (d2 < k2) { k2 = d2; p2 = pos; }
                }
            }
        }
        // no second barrier: parity buffer isolates next round's writes
    }
    __syncthreads();   // s_chosen visibility for gather

    // gather: 32 neighbors x 13 channels; subtract center from ch 4..6
    for (int v = t; v < KK * CC; v += 256) {
        int j = v / CC, c = v - j * CC;
        int pt = s_chosen[j] & (NN - 1);   // safety clamp (no-op when correct)
        float val = x[((size_t)b * NN + pt) * CC + c];
        if (c >= 4 && c < 7) {
            float cs = (c == 4) ? cx : ((c == 5) ? cy : cz);
            val = __fsub_rn(val, cs);
        }
        out[((size_t)bg * KK + j) * CC + c] = val;
    }
}

extern "C" void kernel_launch(void* const* d_in, const int* in_sizes, int n_in,
                              void* d_out, int out_size, void* d_ws, size_t ws_size,
                              hipStream_t stream) {
    const float* x = (const float*)d_in[0];
    float* out = (float*)d_out;
    float* centers = out + NEIGH_ELEMS;   // output 1 follows output 0, flat

    float* px = (float*)d_ws;
    float* py = px + BB * NN;
    float* pz = py + BB * NN;

    pack_kernel<<<(BB * NN + 255) / 256, 256, 0, stream>>>(x, px, py, pz);
    fps_kernel<<<BB, 512, 0, stream>>>(px, py, pz, centers);
    knn_kernel<<<BB * GG, 256, 0, stream>>>(px, py, pz, x, centers, out);
}